// Round 7
// baseline (873.309 us; speedup 1.0000x reference)
//
#include <hip/hip_runtime.h>
#include <hip/hip_bf16.h>
#include <math.h>

#define EPSBN 1e-5f

typedef short short8 __attribute__((ext_vector_type(8)));
typedef float floatx4 __attribute__((ext_vector_type(4)));

__device__ __forceinline__ float gelu_f(float x) {
    return 0.5f * x * (1.0f + erff(x * 0.70710678118654752f));
}

__device__ __forceinline__ unsigned short f2bf(float f) {
    union { float f; unsigned int u; } c; c.f = f;
    unsigned int u = c.u;
    unsigned int r = (u + 0x7FFFu + ((u >> 16) & 1u)) >> 16;   // RNE
    return (unsigned short)r;
}

__device__ __forceinline__ float bf2f(unsigned short h) {
    union { unsigned int u; float f; } c; c.u = ((unsigned int)h) << 16;
    return c.f;
}

// ---------------- weight preps ----------------
// region weights: [G][oc][ic][3][3] fp32 -> [G][oc][t][ic] bf16
__global__ void wprep_bf16_k(const float* __restrict__ w, unsigned short* __restrict__ wb,
                             long total) {
    for (long o = (long)blockIdx.x * blockDim.x + threadIdx.x; o < total;
         o += (long)gridDim.x * blockDim.x) {
        int ic = (int)(o % 192); long t0 = o / 192;
        int t = (int)(t0 % 9); long t1 = t0 / 9;
        int oc = (int)(t1 % 192); long g = t1 / 192;
        wb[o] = f2bf(w[(((size_t)g * 192 + oc) * 192 + ic) * 9 + t]);
    }
}

// downsample weights: [OC][192][2][2] fp32 -> [t4][OC][192] bf16
__global__ void wprep_tap_k(const float* __restrict__ w, unsigned short* __restrict__ wb,
                            int OC) {
    long total = (long)4 * OC * 192;
    for (long o = (long)blockIdx.x * blockDim.x + threadIdx.x; o < total;
         o += (long)gridDim.x * blockDim.x) {
        int ic = (int)(o % 192); long t0 = o / 192;
        int oc = (int)(t0 % OC); int t = (int)(t0 / OC);
        wb[o] = f2bf(w[((size_t)oc * 192 + ic) * 4 + t]);
    }
}

// conv1 weights: [192][48] -> [48][192] fp32
__global__ void wprep_wt1_k(const float* __restrict__ w, float* __restrict__ wt) {
    int o = blockIdx.x * 256 + threadIdx.x;
    if (o < 9216) {
        int oc = o % 192, k = o / 192;
        wt[o] = w[oc * 48 + k];
    }
}

// ---------------- conv1: 3->192, 4x4 stride 4, BN+GELU, NHWC bf16 out ----------------
// block = (b, oy, ox-half); 192 threads = oc
__global__ __launch_bounds__(192) void conv1_k(
        const float* __restrict__ x, const float* __restrict__ wt1,
        const float* __restrict__ bg, const float* __restrict__ bb,
        const float* __restrict__ bm, const float* __restrict__ bv,
        unsigned short* __restrict__ h1c) {
    __shared__ float xs[3][4][112];
    int b = blockIdx.x / 112;
    int rest = blockIdx.x % 112;
    int oy = rest >> 1;
    int ox0 = (rest & 1) * 28;
    int tid = threadIdx.x;
    for (int i = tid; i < 1344; i += 192) {
        int col = i % 112, r = (i / 112) % 4, c = i / 448;
        xs[c][r][col] = x[(((size_t)b * 3 + c) * 224 + 4 * oy + r) * 224 + 4 * ox0 + col];
    }
    float w[48];
    #pragma unroll
    for (int k = 0; k < 48; k++) w[k] = wt1[k * 192 + tid];
    float inv = bg[tid] * rsqrtf(bv[tid] + EPSBN);
    float bet = bb[tid] - bm[tid] * inv;
    __syncthreads();
    for (int ox = 0; ox < 28; ox++) {
        float a = 0.f;
        #pragma unroll
        for (int c = 0; c < 3; c++) {
            #pragma unroll
            for (int ky = 0; ky < 4; ky++) {
                float4 v = *(const float4*)&xs[c][ky][4 * ox];
                const float* wk = &w[(c * 4 + ky) * 4];
                a += v.x * wk[0] + v.y * wk[1] + v.z * wk[2] + v.w * wk[3];
            }
        }
        h1c[(((size_t)b * 56 + oy) * 56 + (ox0 + ox)) * 192 + tid] = f2bf(gelu_f(a * inv + bet));
    }
}

// ---------------- region conv via MFMA v4: halo-free linear tiles, zero-cell taps -------
// block = (g, batch-pair): 4 waves, each wave covers BOTH tiles (8 m-frags of 16 px) and
// a 48-oc quarter. LDS tile = 50 cells (49 px + zero cell) x 200 shorts: cell index == p
// (linear) so ds_read bank groups (cell+quad) mod 8 are uniform -> ~no conflicts.
// Tap edge handling: per-lane address select to the zero cell. t-loop fully unrolled.
#define RST 200
#define NCELL 50
#define TILE_SH (NCELL * RST)    // 10000 shorts = 20000 B
template<int INF32>
__global__ __launch_bounds__(256, 2) void region_mfma4_k(
        const void* __restrict__ inbuf, void* __restrict__ outbuf,
        const unsigned short* __restrict__ wb,
        const float* __restrict__ pg, const float* __restrict__ pb,
        const float* __restrict__ pm, const float* __restrict__ pv,
        int gw, int W) {
    __shared__ unsigned short lds[2 * TILE_SH];   // 40,000 B -> 2 blocks/CU (reg-bound anyway)
    const int raw = blockIdx.x;
    const int g = (raw & 7) + 8 * (raw >> 8);
    const int bp = (raw >> 3) & 31;
    const int b0 = bp * 2;
    const int gy = g / gw, gx = g % gw;
    const int Y0 = gy * 7, X0 = gx * 7;
    const int tid = threadIdx.x;
    const int lane = tid & 63;
    const int wid = tid >> 6;
    const int quad = lane >> 4;
    const int l15 = lane & 15;

    const size_t tsz = (size_t)W * W * 192;
    const size_t slab0 = (size_t)b0 * tsz;

    // zero cell 49 of each tile
    for (int i = tid; i < 48; i += 256) {
        int tI = i / 24, ch = i % 24;
        *(short8*)&lds[tI * TILE_SH + 49 * RST + ch * 8] = (short8)0;
    }
    // interior fill: cell index == pixel index p (0..48), b128 per lane
    for (int i = tid; i < 2352; i += 256) {
        int tI = i / 1176, rem = i % 1176, p = rem / 24, ch = rem % 24;
        int y = p / 7, xx = p % 7;
        size_t poff = slab0 + (size_t)tI * tsz + ((size_t)(Y0 + y) * W + (X0 + xx)) * 192 + ch * 8;
        short8 v;
        if (INF32) {
            const float* s4 = (const float*)inbuf + poff;
            float4 a = *(const float4*)s4;
            float4 b2 = *(const float4*)(s4 + 4);
            v[0] = (short)f2bf(a.x);  v[1] = (short)f2bf(a.y);
            v[2] = (short)f2bf(a.z);  v[3] = (short)f2bf(a.w);
            v[4] = (short)f2bf(b2.x); v[5] = (short)f2bf(b2.y);
            v[6] = (short)f2bf(b2.z); v[7] = (short)f2bf(b2.w);
        } else {
            v = *(const short8*)((const unsigned short*)inbuf + poff);
        }
        *(short8*)&lds[tI * TILE_SH + p * RST + ch * 8] = v;
    }
    __syncthreads();

    // per-lane m-frag pixel coords (per tile; same for both tiles)
    int pyv[4], pxv[4];
    #pragma unroll
    for (int f = 0; f < 4; f++) {
        int p = f * 16 + l15; if (p > 48) p = 48;
        pyv[f] = p / 7; pxv[f] = p % 7;
    }
    // weight offsets: oc = wid*48 + nt*16 + l15
    int woff[3];
    #pragma unroll
    for (int nt = 0; nt < 3; nt++)
        woff[nt] = (wid * 48 + nt * 16 + l15) * 1728 + quad * 8;
    const unsigned short* wbg = wb + (size_t)g * 331776;

    floatx4 acc[8][3];
    #pragma unroll
    for (int m = 0; m < 8; m++)
        #pragma unroll
        for (int nt = 0; nt < 3; nt++) acc[m][nt] = (floatx4)0.f;

    #pragma unroll
    for (int t = 0; t < 9; t++) {
        const int dy = t / 3 - 1, dx = t % 3 - 1;
        int ca[8];
        #pragma unroll
        for (int f = 0; f < 4; f++) {
            int yy = pyv[f] + dy, xx2 = pxv[f] + dx;
            bool ok = ((unsigned)yy < 7u) & ((unsigned)xx2 < 7u);
            int cell = ok ? (yy * 7 + xx2) : 49;
            ca[f] = cell * RST + quad * 8;
            ca[4 + f] = TILE_SH + ca[f];
        }
        const int toff = t * 192;
        #pragma unroll
        for (int s = 0; s < 6; s++) {
            const int ic0 = s * 32;
            short8 wf[3];
            #pragma unroll
            for (int nt = 0; nt < 3; nt++)
                wf[nt] = *(const short8*)(wbg + woff[nt] + toff + ic0);
            short8 pf[8];
            #pragma unroll
            for (int m = 0; m < 8; m++)
                pf[m] = *(const short8*)&lds[ca[m] + ic0];
            #pragma unroll
            for (int m = 0; m < 8; m++)
                #pragma unroll
                for (int nt = 0; nt < 3; nt++)
                    acc[m][nt] = __builtin_amdgcn_mfma_f32_16x16x32_bf16(pf[m], wf[nt], acc[m][nt], 0, 0, 0);
        }
    }

    // epilogue: C row = pixel (f*16 + quad*4 + r), col = oc (l15). Residual from global.
    #pragma unroll
    for (int nt = 0; nt < 3; nt++) {
        int oc = wid * 48 + nt * 16 + l15;
        float inv = pg[g * 192 + oc] * rsqrtf(pv[g * 192 + oc] + EPSBN);
        float bet = pb[g * 192 + oc] - pm[g * 192 + oc] * inv;
        #pragma unroll
        for (int m = 0; m < 8; m++) {
            const int tI = m >> 2;
            const int f = m & 3;
            const size_t tslab = slab0 + (size_t)tI * tsz;
            unsigned short* outb = (unsigned short*)outbuf + tslab;
            const float* resf = (const float*)inbuf + tslab;
            const unsigned short* resu = (const unsigned short*)inbuf + tslab;
            #pragma unroll
            for (int r = 0; r < 4; r++) {
                int p = f * 16 + quad * 4 + r;
                if (p < 49) {
                    int y = p / 7, xx = p % 7;
                    size_t pix = (size_t)(Y0 + y) * W + (X0 + xx);
                    float res = INF32 ? resf[pix * 192 + oc] : bf2f(resu[pix * 192 + oc]);
                    outb[pix * 192 + oc] = f2bf(gelu_f(acc[m][nt][r] * inv + bet) + res);
                }
            }
        }
    }
}

// ---------------- conv2 via MFMA (no LDS): 192->192, 2x2 s2, BN+GELU -------------------
// A-frags read directly from global NHWC (stride-2 conv has zero input reuse).
__global__ __launch_bounds__(256) void conv2_mfma_k(
        const unsigned short* __restrict__ h1c, const unsigned short* __restrict__ wb,
        const float* __restrict__ bg, const float* __restrict__ bb,
        const float* __restrict__ bm, const float* __restrict__ bv,
        float* __restrict__ h2c) {
    const int b = blockIdx.x / 7;
    const int oy0 = (blockIdx.x % 7) * 4;
    const int tid = threadIdx.x;
    const int lane = tid & 63;
    const int wid = tid >> 6;
    const int quad = lane >> 4;
    const int l15 = lane & 15;

    // per-lane pixel base offsets (input top-left of 2x2 window), +quad ic-offset
    size_t pixoff[7];
    #pragma unroll
    for (int mt = 0; mt < 7; mt++) {
        int p = mt * 16 + l15;
        int oy = oy0 + p / 28, ox = p % 28;
        pixoff[mt] = (((size_t)b * 56 + 2 * oy) * 56 + 2 * ox) * 192 + quad * 8;
    }

    floatx4 acc[7][3];
    #pragma unroll
    for (int mt = 0; mt < 7; mt++)
        #pragma unroll
        for (int nt = 0; nt < 3; nt++) acc[mt][nt] = (floatx4)0.f;

    #pragma unroll
    for (int ky = 0; ky < 2; ky++) {
        #pragma unroll
        for (int kx = 0; kx < 2; kx++) {
            const int t = ky * 2 + kx;
            const size_t aoff = ((size_t)ky * 56 + kx) * 192;
            #pragma unroll
            for (int c = 0; c < 6; c++) {
                short8 wf[3];
                #pragma unroll
                for (int nt = 0; nt < 3; nt++) {
                    int oc = wid * 48 + nt * 16 + l15;
                    wf[nt] = *(const short8*)(wb + ((size_t)(t * 192 + oc)) * 192 + c * 32 + quad * 8);
                }
                short8 ap[7];
                #pragma unroll
                for (int mt = 0; mt < 7; mt++)
                    ap[mt] = *(const short8*)(h1c + pixoff[mt] + aoff + c * 32);
                #pragma unroll
                for (int mt = 0; mt < 7; mt++)
                    #pragma unroll
                    for (int nt = 0; nt < 3; nt++)
                        acc[mt][nt] = __builtin_amdgcn_mfma_f32_16x16x32_bf16(ap[mt], wf[nt], acc[mt][nt], 0, 0, 0);
            }
        }
    }
    #pragma unroll
    for (int nt = 0; nt < 3; nt++) {
        int oc = wid * 48 + nt * 16 + l15;
        float inv = bg[oc] * rsqrtf(bv[oc] + EPSBN);
        float bet = bb[oc] - bm[oc] * inv;
        #pragma unroll
        for (int mt = 0; mt < 7; mt++) {
            #pragma unroll
            for (int r = 0; r < 4; r++) {
                int p = mt * 16 + quad * 4 + r;
                int oy = oy0 + p / 28, ox = p % 28;
                h2c[(((size_t)b * 28 + oy) * 28 + ox) * 192 + oc] = gelu_f(acc[mt][nt][r] * inv + bet);
            }
        }
    }
}

// ---------------- conv3 via MFMA (no LDS): 192->768, 2x2 s2, BN -> out (B,196,768) -----
__global__ __launch_bounds__(256) void conv3_mfma_k(
        const unsigned short* __restrict__ h2b, const unsigned short* __restrict__ wb,
        const float* __restrict__ bg, const float* __restrict__ bb,
        const float* __restrict__ bm, const float* __restrict__ bv,
        float* __restrict__ out) {
    const int bid = blockIdx.x;
    const int b = bid / 6;
    const int s = (bid % 6) / 3;
    const int octile = bid % 3;
    const int y0 = s * 7;
    const int tid = threadIdx.x;
    const int lane = tid & 63;
    const int wid = tid >> 6;
    const int quad = lane >> 4;
    const int l15 = lane & 15;

    size_t pixoff[7];
    #pragma unroll
    for (int mt = 0; mt < 7; mt++) {
        int p = mt * 16 + l15; if (p > 97) p = 97;
        int oy = y0 + p / 14, ox = p % 14;
        pixoff[mt] = (((size_t)b * 28 + 2 * oy) * 28 + 2 * ox) * 192 + quad * 8;
    }

    floatx4 acc[7][4];
    #pragma unroll
    for (int mt = 0; mt < 7; mt++)
        #pragma unroll
        for (int nt = 0; nt < 4; nt++) acc[mt][nt] = (floatx4)0.f;

    #pragma unroll
    for (int ky = 0; ky < 2; ky++) {
        #pragma unroll
        for (int kx = 0; kx < 2; kx++) {
            const int t = ky * 2 + kx;
            const size_t aoff = ((size_t)ky * 28 + kx) * 192;
            #pragma unroll
            for (int c = 0; c < 6; c++) {
                short8 wf[4];
                #pragma unroll
                for (int nt = 0; nt < 4; nt++) {
                    int oc = octile * 256 + wid * 64 + nt * 16 + l15;
                    wf[nt] = *(const short8*)(wb + ((size_t)(t * 768 + oc)) * 192 + c * 32 + quad * 8);
                }
                short8 ap[7];
                #pragma unroll
                for (int mt = 0; mt < 7; mt++)
                    ap[mt] = *(const short8*)(h2b + pixoff[mt] + aoff + c * 32);
                #pragma unroll
                for (int mt = 0; mt < 7; mt++)
                    #pragma unroll
                    for (int nt = 0; nt < 4; nt++)
                        acc[mt][nt] = __builtin_amdgcn_mfma_f32_16x16x32_bf16(ap[mt], wf[nt], acc[mt][nt], 0, 0, 0);
            }
        }
    }
    #pragma unroll
    for (int nt = 0; nt < 4; nt++) {
        int oc = octile * 256 + wid * 64 + nt * 16 + l15;
        float inv = bg[oc] * rsqrtf(bv[oc] + EPSBN);
        float bet = bb[oc] - bm[oc] * inv;
        #pragma unroll
        for (int mt = 0; mt < 7; mt++) {
            #pragma unroll
            for (int r = 0; r < 4; r++) {
                int p = mt * 16 + quad * 4 + r;
                if (p < 98) {
                    int oy = y0 + p / 14, ox = p % 14;
                    out[((size_t)b * 196 + oy * 14 + ox) * 768 + oc] = acc[mt][nt][r] * inv + bet;
                }
            }
        }
    }
}

extern "C" void kernel_launch(void* const* d_in, const int* in_sizes, int n_in,
                              void* d_out, int out_size, void* d_ws, size_t ws_size,
                              hipStream_t stream) {
    const float* x   = (const float*)d_in[0];
    const float* w1  = (const float*)d_in[1];
    const float* b1g = (const float*)d_in[2];
    const float* b1b = (const float*)d_in[3];
    const float* b1m = (const float*)d_in[4];
    const float* b1v = (const float*)d_in[5];
    const float* r1w = (const float*)d_in[6];
    const float* r1g = (const float*)d_in[7];
    const float* r1b = (const float*)d_in[8];
    const float* r1m = (const float*)d_in[9];
    const float* r1v = (const float*)d_in[10];
    const float* w2  = (const float*)d_in[11];
    const float* b2g = (const float*)d_in[12];
    const float* b2b = (const float*)d_in[13];
    const float* b2m = (const float*)d_in[14];
    const float* b2v = (const float*)d_in[15];
    const float* r2w = (const float*)d_in[16];
    const float* r2g = (const float*)d_in[17];
    const float* r2b = (const float*)d_in[18];
    const float* r2m = (const float*)d_in[19];
    const float* r2v = (const float*)d_in[20];
    const float* w3  = (const float*)d_in[21];
    const float* b3g = (const float*)d_in[22];
    const float* b3b = (const float*)d_in[23];
    const float* b3m = (const float*)d_in[24];
    const float* b3v = (const float*)d_in[25];
    float* out = (float*)d_out;

    char* ws = (char*)d_ws;
    unsigned short* h1c  = (unsigned short*)(ws + 0);            // 77,070,336  bf16 NHWC 56x56
    float*          h2c  = (float*)         (ws + 77070336UL);   // 38,535,168  fp32 NHWC 28x28
    unsigned short* h2b  = (unsigned short*)(ws + 115605504UL);  // 19,267,584  bf16 NHWC 28x28
    unsigned short* wb1  = (unsigned short*)(ws + 134873088UL);  // 42,467,328
    unsigned short* wb2r = (unsigned short*)(ws + 177340416UL);  // 10,616,832
    float*          wt1  = (float*)         (ws + 187957248UL);  //     36,864
    unsigned short* wb2c = (unsigned short*)(ws + 187994112UL);  //    294,912
    unsigned short* wb3c = (unsigned short*)(ws + 188289024UL);  //  1,179,648
    // total 189,468,672 B

    wprep_bf16_k<<<8192, 256, 0, stream>>>(r1w, wb1, (long)64 * 192 * 9 * 192);
    wprep_bf16_k<<<2048, 256, 0, stream>>>(r2w, wb2r, (long)16 * 192 * 9 * 192);
    wprep_tap_k<<<576, 256, 0, stream>>>(w2, wb2c, 192);
    wprep_tap_k<<<2304, 256, 0, stream>>>(w3, wb3c, 768);
    wprep_wt1_k<<<36, 256, 0, stream>>>(w1, wt1);

    conv1_k<<<64 * 112, 192, 0, stream>>>(x, wt1, b1g, b1b, b1m, b1v, h1c);
    region_mfma4_k<0><<<64 * 32, 256, 0, stream>>>(h1c, h1c, wb1, r1g, r1b, r1m, r1v, 8, 56);
    conv2_mfma_k<<<64 * 7, 256, 0, stream>>>(h1c, wb2c, b2g, b2b, b2m, b2v, h2c);
    region_mfma4_k<1><<<16 * 32, 256, 0, stream>>>(h2c, h2b, wb2r, r2g, r2b, r2m, r2v, 4, 28);
    conv3_mfma_k<<<64 * 6, 256, 0, stream>>>(h2b, wb3c, b3g, b3b, b3m, b3v, out);
}